// Round 1
// baseline (20220.149 us; speedup 1.0000x reference)
//
#include <hip/hip_runtime.h>

// LightGCN-style 3-layer bipartite propagation.
// u_next[rows[e]] += vals[e] * it[cols[e]] ; i_next[cols[e]] += vals[e] * u[rows[e]]
// Both SpMMs of a layer read the PREVIOUS layer's u/it -> fuse into one edge pass.

#define NUM_USERS 100000
#define NUM_ITEMS 50000
#define EMBED_DIM 128
#define NNZ_COUNT 2000000

// One edge per 32-lane group; each lane handles 4 consecutive floats (float4).
// Block 256 = 8 edges. Gathers are 512B-contiguous per edge (coalesced dwordx4).
__global__ __launch_bounds__(256) void edge_spmm(
    const float* __restrict__ vals,
    const int*   __restrict__ rows,
    const int*   __restrict__ cols,
    const float* __restrict__ u_src,
    const float* __restrict__ i_src,
    float*       __restrict__ u_dst,
    float*       __restrict__ i_dst,
    int nnz)
{
    const int lane = threadIdx.x & 31;
    const int e = blockIdx.x * 8 + (threadIdx.x >> 5);
    if (e >= nnz) return;

    const float v = vals[e];
    const int r = rows[e];
    const int c = cols[e];

    const long ro = (long)r * EMBED_DIM + lane * 4;
    const long co = (long)c * EMBED_DIM + lane * 4;

    const float4 iv = *reinterpret_cast<const float4*>(i_src + co);
    const float4 uv = *reinterpret_cast<const float4*>(u_src + ro);

    atomicAdd(u_dst + ro + 0, v * iv.x);
    atomicAdd(u_dst + ro + 1, v * iv.y);
    atomicAdd(u_dst + ro + 2, v * iv.z);
    atomicAdd(u_dst + ro + 3, v * iv.w);

    atomicAdd(i_dst + co + 0, v * uv.x);
    atomicAdd(i_dst + co + 1, v * uv.y);
    atomicAdd(i_dst + co + 2, v * uv.z);
    atomicAdd(i_dst + co + 3, v * uv.w);
}

// out = (out + x) * scale, vectorized float4. n is a multiple of 1024.
__global__ __launch_bounds__(256) void acc_scale(
    float* __restrict__ out, const float* __restrict__ x, long n, float scale)
{
    long i = ((long)blockIdx.x * blockDim.x + threadIdx.x) * 4;
    if (i >= n) return;
    float4 o = *reinterpret_cast<float4*>(out + i);
    float4 a = *reinterpret_cast<const float4*>(x + i);
    o.x = (o.x + a.x) * scale;
    o.y = (o.y + a.y) * scale;
    o.z = (o.z + a.z) * scale;
    o.w = (o.w + a.w) * scale;
    *reinterpret_cast<float4*>(out + i) = o;
}

extern "C" void kernel_launch(void* const* d_in, const int* in_sizes, int n_in,
                              void* d_out, int out_size, void* d_ws, size_t ws_size,
                              hipStream_t stream)
{
    const float* user = (const float*)d_in[0];
    const float* item = (const float*)d_in[1];
    const float* vals = (const float*)d_in[2];
    const int*   rows = (const int*)d_in[3];
    const int*   cols = (const int*)d_in[4];

    const size_t UD = (size_t)NUM_USERS * EMBED_DIM;   // 12,800,000
    const size_t ID = (size_t)NUM_ITEMS * EMBED_DIM;   //  6,400,000

    float* out_u = (float*)d_out;
    float* out_i = out_u + UD;

    float* uA = (float*)d_ws;
    float* uB = uA + UD;
    float* iA = uB + UD;
    float* iB = iA + ID;

    const int EDGE_BLOCKS = (NNZ_COUNT + 7) / 8;       // 250,000
    const int ACC_U = (int)(UD / 1024);                // 12,500
    const int ACC_I = (int)(ID / 1024);                //  6,250

    // out_sum starts at layer-0 embeddings
    hipMemcpyAsync(out_u, user, UD * sizeof(float), hipMemcpyDeviceToDevice, stream);
    hipMemcpyAsync(out_i, item, ID * sizeof(float), hipMemcpyDeviceToDevice, stream);

    // ---- layer 1: read (user,item) -> write (uA,iA)
    hipMemsetAsync(uA, 0, UD * sizeof(float), stream);
    hipMemsetAsync(iA, 0, ID * sizeof(float), stream);
    edge_spmm<<<EDGE_BLOCKS, 256, 0, stream>>>(vals, rows, cols, user, item, uA, iA, NNZ_COUNT);
    acc_scale<<<ACC_U, 256, 0, stream>>>(out_u, uA, (long)UD, 1.0f);
    acc_scale<<<ACC_I, 256, 0, stream>>>(out_i, iA, (long)ID, 1.0f);

    // ---- layer 2: read (uA,iA) -> write (uB,iB)
    hipMemsetAsync(uB, 0, UD * sizeof(float), stream);
    hipMemsetAsync(iB, 0, ID * sizeof(float), stream);
    edge_spmm<<<EDGE_BLOCKS, 256, 0, stream>>>(vals, rows, cols, uA, iA, uB, iB, NNZ_COUNT);
    acc_scale<<<ACC_U, 256, 0, stream>>>(out_u, uB, (long)UD, 1.0f);
    acc_scale<<<ACC_I, 256, 0, stream>>>(out_i, iB, (long)ID, 1.0f);

    // ---- layer 3: read (uB,iB) -> write (uA,iA); fold final /4 into the add
    hipMemsetAsync(uA, 0, UD * sizeof(float), stream);
    hipMemsetAsync(iA, 0, ID * sizeof(float), stream);
    edge_spmm<<<EDGE_BLOCKS, 256, 0, stream>>>(vals, rows, cols, uB, iB, uA, iA, NNZ_COUNT);
    acc_scale<<<ACC_U, 256, 0, stream>>>(out_u, uA, (long)UD, 0.25f);
    acc_scale<<<ACC_I, 256, 0, stream>>>(out_i, iA, (long)ID, 0.25f);
}

// Round 2
// 1781.680 us; speedup vs baseline: 11.3489x; 11.3489x over previous
//
#include <hip/hip_runtime.h>

// LightGCN-style 3-layer bipartite propagation, CSR segmented-sum version.
// Round-1 counters showed the atomic edge kernel is atomic-throughput-bound
// (WRITE_SIZE 8 GB/dispatch for 77 MB of payload, VALUBusy 0.7%). Fix: build
// CSR once per launch (rows/cols are layer-invariant), then 6 atomic-free
// wave-per-row SpMMs with the layer-sum accumulation fused into the epilogue.

#define NUM_USERS 100000
#define NUM_ITEMS 50000
#define EMBED_DIM 128
#define NNZ_COUNT 2000000

// ---------------- CSR build ----------------

__global__ __launch_bounds__(256) void histo_kernel(
    const int* __restrict__ rows, const int* __restrict__ cols,
    int* __restrict__ cnt_u, int* __restrict__ cnt_i, int nnz)
{
    int e = blockIdx.x * blockDim.x + threadIdx.x;
    if (e >= nnz) return;
    atomicAdd(&cnt_u[rows[e]], 1);
    atomicAdd(&cnt_i[cols[e]], 1);
}

// Single-block exclusive scan. In-place: cnt[i] becomes row start offset
// (kept as the scatter cursor), ptr[0..n] gets the CSR row pointers.
__global__ __launch_bounds__(1024) void ex_scan_kernel(
    int* __restrict__ cnt, int* __restrict__ ptr, int n)
{
    __shared__ int buf[1024];
    __shared__ int s_carry;
    const int t = threadIdx.x;
    if (t == 0) s_carry = 0;
    __syncthreads();
    for (int base = 0; base < n; base += 1024) {
        const int idx = base + t;
        const int x = (idx < n) ? cnt[idx] : 0;
        buf[t] = x;
        __syncthreads();
        for (int d = 1; d < 1024; d <<= 1) {
            int y = (t >= d) ? buf[t - d] : 0;
            __syncthreads();
            buf[t] += y;
            __syncthreads();
        }
        const int exc = buf[t] - x;       // exclusive within chunk
        const int carry = s_carry;
        if (idx < n) { int o = carry + exc; ptr[idx] = o; cnt[idx] = o; }
        __syncthreads();
        if (t == 1023) s_carry = carry + buf[1023];
        __syncthreads();
    }
    if (t == 0) ptr[n] = s_carry;
}

__global__ __launch_bounds__(256) void scatter_kernel(
    const int* __restrict__ rows, const int* __restrict__ cols,
    const float* __restrict__ vals,
    int* __restrict__ off_u, int* __restrict__ off_i,
    int2* __restrict__ pairs_u, int2* __restrict__ pairs_i, int nnz)
{
    int e = blockIdx.x * blockDim.x + threadIdx.x;
    if (e >= nnz) return;
    const int r = rows[e];
    const int c = cols[e];
    const int vb = __float_as_int(vals[e]);
    const int pu = atomicAdd(&off_u[r], 1);
    pairs_u[pu] = make_int2(c, vb);
    const int pi = atomicAdd(&off_i[c], 1);
    pairs_i[pi] = make_int2(r, vb);
}

// ---------------- SpMM: one 64-lane wave per destination row ----------------
// Lane l owns dims [2l, 2l+1] (float2). Edge (neighbor,val) pairs are loaded
// coalesced (one pair per lane per 64-edge chunk) and broadcast via __shfl.
// Epilogue: dst[row] = acc; out_sum[row] = (out_sum[row] + acc) * scale.
__global__ __launch_bounds__(256) void csr_spmm_kernel(
    const int*  __restrict__ ptr,
    const int2* __restrict__ pairs,
    const float* __restrict__ src,
    float* __restrict__ dst,
    float* __restrict__ out_sum,
    int nrows, float scale)
{
    const int wave = (int)((blockIdx.x * blockDim.x + threadIdx.x) >> 6);
    const int lane = threadIdx.x & 63;
    if (wave >= nrows) return;

    const int start = ptr[wave];
    const int end   = ptr[wave + 1];

    float2 acc = make_float2(0.f, 0.f);

    for (int chunk = start; chunk < end; chunk += 64) {
        int idx = chunk + lane;
        int2 p = make_int2(0, 0);
        if (idx < end) p = pairs[idx];
        int m = end - chunk; if (m > 64) m = 64;

        int j = 0;
        for (; j + 4 <= m; j += 4) {
            const int   c0 = __shfl(p.x, j),     c1 = __shfl(p.x, j + 1);
            const int   c2 = __shfl(p.x, j + 2), c3 = __shfl(p.x, j + 3);
            const float v0 = __int_as_float(__shfl(p.y, j));
            const float v1 = __int_as_float(__shfl(p.y, j + 1));
            const float v2 = __int_as_float(__shfl(p.y, j + 2));
            const float v3 = __int_as_float(__shfl(p.y, j + 3));
            const float2 s0 = *reinterpret_cast<const float2*>(src + (size_t)c0 * EMBED_DIM + (lane << 1));
            const float2 s1 = *reinterpret_cast<const float2*>(src + (size_t)c1 * EMBED_DIM + (lane << 1));
            const float2 s2 = *reinterpret_cast<const float2*>(src + (size_t)c2 * EMBED_DIM + (lane << 1));
            const float2 s3 = *reinterpret_cast<const float2*>(src + (size_t)c3 * EMBED_DIM + (lane << 1));
            acc.x += v0 * s0.x; acc.y += v0 * s0.y;
            acc.x += v1 * s1.x; acc.y += v1 * s1.y;
            acc.x += v2 * s2.x; acc.y += v2 * s2.y;
            acc.x += v3 * s3.x; acc.y += v3 * s3.y;
        }
        for (; j < m; ++j) {
            const int   c = __shfl(p.x, j);
            const float v = __int_as_float(__shfl(p.y, j));
            const float2 s = *reinterpret_cast<const float2*>(src + (size_t)c * EMBED_DIM + (lane << 1));
            acc.x += v * s.x; acc.y += v * s.y;
        }
    }

    const size_t o = (size_t)wave * EMBED_DIM + (lane << 1);
    *reinterpret_cast<float2*>(dst + o) = acc;
    float2 os = *reinterpret_cast<const float2*>(out_sum + o);
    os.x = (os.x + acc.x) * scale;
    os.y = (os.y + acc.y) * scale;
    *reinterpret_cast<float2*>(out_sum + o) = os;
}

// ---------------- fallback (round-1 atomic path) ----------------

__global__ __launch_bounds__(256) void edge_spmm(
    const float* __restrict__ vals, const int* __restrict__ rows,
    const int* __restrict__ cols, const float* __restrict__ u_src,
    const float* __restrict__ i_src, float* __restrict__ u_dst,
    float* __restrict__ i_dst, int nnz)
{
    const int lane = threadIdx.x & 31;
    const int e = blockIdx.x * 8 + (threadIdx.x >> 5);
    if (e >= nnz) return;
    const float v = vals[e];
    const size_t ro = (size_t)rows[e] * EMBED_DIM + lane * 4;
    const size_t co = (size_t)cols[e] * EMBED_DIM + lane * 4;
    const float4 iv = *reinterpret_cast<const float4*>(i_src + co);
    const float4 uv = *reinterpret_cast<const float4*>(u_src + ro);
    atomicAdd(u_dst + ro + 0, v * iv.x); atomicAdd(u_dst + ro + 1, v * iv.y);
    atomicAdd(u_dst + ro + 2, v * iv.z); atomicAdd(u_dst + ro + 3, v * iv.w);
    atomicAdd(i_dst + co + 0, v * uv.x); atomicAdd(i_dst + co + 1, v * uv.y);
    atomicAdd(i_dst + co + 2, v * uv.z); atomicAdd(i_dst + co + 3, v * uv.w);
}

__global__ __launch_bounds__(256) void acc_scale(
    float* __restrict__ out, const float* __restrict__ x, long n, float scale)
{
    long i = ((long)blockIdx.x * blockDim.x + threadIdx.x) * 4;
    if (i >= n) return;
    float4 o = *reinterpret_cast<float4*>(out + i);
    float4 a = *reinterpret_cast<const float4*>(x + i);
    o.x = (o.x + a.x) * scale; o.y = (o.y + a.y) * scale;
    o.z = (o.z + a.z) * scale; o.w = (o.w + a.w) * scale;
    *reinterpret_cast<float4*>(out + i) = o;
}

// ---------------- launch ----------------

extern "C" void kernel_launch(void* const* d_in, const int* in_sizes, int n_in,
                              void* d_out, int out_size, void* d_ws, size_t ws_size,
                              hipStream_t stream)
{
    const float* user = (const float*)d_in[0];
    const float* item = (const float*)d_in[1];
    const float* vals = (const float*)d_in[2];
    const int*   rows = (const int*)d_in[3];
    const int*   cols = (const int*)d_in[4];

    const size_t UD = (size_t)NUM_USERS * EMBED_DIM;   // 12.8M floats
    const size_t ID = (size_t)NUM_ITEMS * EMBED_DIM;   //  6.4M floats

    float* out_u = (float*)d_out;
    float* out_i = out_u + UD;

    // workspace layout
    char* ws = (char*)d_ws;
    float* uA = (float*)ws;                         ws += UD * 4;
    float* uB = (float*)ws;                         ws += UD * 4;
    float* iA = (float*)ws;                         ws += ID * 4;
    float* iB = (float*)ws;                         ws += ID * 4;
    int2* pairs_u = (int2*)ws;                      ws += (size_t)NNZ_COUNT * 8;
    int2* pairs_i = (int2*)ws;                      ws += (size_t)NNZ_COUNT * 8;
    int* ptr_u = (int*)ws;                          ws += (NUM_USERS + 1) * 4;
    int* cnt_u = (int*)ws;                          ws += NUM_USERS * 4;
    int* ptr_i = (int*)ws;                          ws += (NUM_ITEMS + 1) * 4;
    int* cnt_i = (int*)ws;                          ws += NUM_ITEMS * 4;
    const size_t REQ = (size_t)(ws - (char*)d_ws);

    // out_sum starts at layer-0 embeddings
    hipMemcpyAsync(out_u, user, UD * 4, hipMemcpyDeviceToDevice, stream);
    hipMemcpyAsync(out_i, item, ID * 4, hipMemcpyDeviceToDevice, stream);

    const int EB = (NNZ_COUNT + 255) / 256;

    if (ws_size >= REQ) {
        // ---- CSR build (rows/cols layer-invariant: build once, use 6x) ----
        hipMemsetAsync(cnt_u, 0, NUM_USERS * 4, stream);
        hipMemsetAsync(cnt_i, 0, NUM_ITEMS * 4, stream);
        histo_kernel<<<EB, 256, 0, stream>>>(rows, cols, cnt_u, cnt_i, NNZ_COUNT);
        ex_scan_kernel<<<1, 1024, 0, stream>>>(cnt_u, ptr_u, NUM_USERS);
        ex_scan_kernel<<<1, 1024, 0, stream>>>(cnt_i, ptr_i, NUM_ITEMS);
        scatter_kernel<<<EB, 256, 0, stream>>>(rows, cols, vals, cnt_u, cnt_i,
                                               pairs_u, pairs_i, NNZ_COUNT);

        const int GU = (NUM_USERS + 3) / 4;   // 4 waves (rows) per 256-thread block
        const int GI = (NUM_ITEMS + 3) / 4;

        // layer 1: src = inputs
        csr_spmm_kernel<<<GU, 256, 0, stream>>>(ptr_u, pairs_u, item, uA, out_u, NUM_USERS, 1.0f);
        csr_spmm_kernel<<<GI, 256, 0, stream>>>(ptr_i, pairs_i, user, iA, out_i, NUM_ITEMS, 1.0f);
        // layer 2
        csr_spmm_kernel<<<GU, 256, 0, stream>>>(ptr_u, pairs_u, iA, uB, out_u, NUM_USERS, 1.0f);
        csr_spmm_kernel<<<GI, 256, 0, stream>>>(ptr_i, pairs_i, uA, iB, out_i, NUM_ITEMS, 1.0f);
        // layer 3 (+ final /4 fused)
        csr_spmm_kernel<<<GU, 256, 0, stream>>>(ptr_u, pairs_u, iB, uA, out_u, NUM_USERS, 0.25f);
        csr_spmm_kernel<<<GI, 256, 0, stream>>>(ptr_i, pairs_i, uB, iA, out_i, NUM_ITEMS, 0.25f);
    } else {
        // ---- fallback: round-1 atomic path (needs 153.6 MB, known to fit) ----
        const int EDGE_BLOCKS = (NNZ_COUNT + 7) / 8;
        const int ACC_U = (int)(UD / 1024), ACC_I = (int)(ID / 1024);

        hipMemsetAsync(uA, 0, UD * 4, stream);
        hipMemsetAsync(iA, 0, ID * 4, stream);
        edge_spmm<<<EDGE_BLOCKS, 256, 0, stream>>>(vals, rows, cols, user, item, uA, iA, NNZ_COUNT);
        acc_scale<<<ACC_U, 256, 0, stream>>>(out_u, uA, (long)UD, 1.0f);
        acc_scale<<<ACC_I, 256, 0, stream>>>(out_i, iA, (long)ID, 1.0f);

        hipMemsetAsync(uB, 0, UD * 4, stream);
        hipMemsetAsync(iB, 0, ID * 4, stream);
        edge_spmm<<<EDGE_BLOCKS, 256, 0, stream>>>(vals, rows, cols, uA, iA, uB, iB, NNZ_COUNT);
        acc_scale<<<ACC_U, 256, 0, stream>>>(out_u, uB, (long)UD, 1.0f);
        acc_scale<<<ACC_I, 256, 0, stream>>>(out_i, iB, (long)ID, 1.0f);

        hipMemsetAsync(uA, 0, UD * 4, stream);
        hipMemsetAsync(iA, 0, ID * 4, stream);
        edge_spmm<<<EDGE_BLOCKS, 256, 0, stream>>>(vals, rows, cols, uB, iB, uA, iA, NNZ_COUNT);
        acc_scale<<<ACC_U, 256, 0, stream>>>(out_u, uA, (long)UD, 0.25f);
        acc_scale<<<ACC_I, 256, 0, stream>>>(out_i, iA, (long)ID, 0.25f);
    }
}

// Round 3
// 1433.473 us; speedup vs baseline: 14.1057x; 1.2429x over previous
//
#include <hip/hip_runtime.h>

// LightGCN-style 3-layer bipartite propagation, CSR segmented-sum version.
// R2 counters: scatter_kernel ~355us (random 8B writes, 64B-line amplified,
// WRITE_SIZE 241MB for 32MB payload); single-block scans serialize on 1 CU.
// R3: multi-block 3-phase scan, fuse out_sum init into layer-1 epilogue,
// merge U/I SpMMs per layer into one dual dispatch.

#define NUM_USERS 100000
#define NUM_ITEMS 50000
#define EMBED_DIM 128
#define NNZ_COUNT 2000000
#define SCAN_CHUNK 4096

// ---------------- CSR build ----------------

__global__ __launch_bounds__(256) void histo_kernel(
    const int* __restrict__ rows, const int* __restrict__ cols,
    int* __restrict__ cnt_u, int* __restrict__ cnt_i, int nnz)
{
    int e = blockIdx.x * blockDim.x + threadIdx.x;
    if (e >= nnz) return;
    atomicAdd(&cnt_u[rows[e]], 1);
    atomicAdd(&cnt_i[cols[e]], 1);
}

// Phase 1: per-chunk partial sums (chunk = SCAN_CHUNK elements).
__global__ __launch_bounds__(256) void scan_partial_sums(
    const int* __restrict__ cnt, int* __restrict__ partials, int n)
{
    const int base = blockIdx.x * SCAN_CHUNK;
    int s = 0;
    for (int i = threadIdx.x; i < SCAN_CHUNK; i += 256) {
        const int idx = base + i;
        if (idx < n) s += cnt[idx];
    }
    for (int d = 32; d; d >>= 1) s += __shfl_down(s, d);
    __shared__ int red[4];
    if ((threadIdx.x & 63) == 0) red[threadIdx.x >> 6] = s;
    __syncthreads();
    if (threadIdx.x == 0) partials[blockIdx.x] = red[0] + red[1] + red[2] + red[3];
}

// Phase 2: serial exclusive scan of <=32 partials; writes grand total to ptr[n].
__global__ void scan_partials_kernel(int* __restrict__ partials,
                                     int* __restrict__ ptr_n, int nb)
{
    if (threadIdx.x == 0) {
        int run = 0;
        for (int b = 0; b < nb; ++b) { int x = partials[b]; partials[b] = run; run += x; }
        *ptr_n = run;
    }
}

// Phase 3: per-chunk exclusive scan (+chunk offset). Writes ptr[] and the
// scatter cursor in-place into cnt[] (each block touches only its own chunk).
__global__ __launch_bounds__(256) void scan_chunk_kernel(
    int* __restrict__ cnt, const int* __restrict__ partials,
    int* __restrict__ ptr, int n)
{
    __shared__ int tsum[256];
    const int t = threadIdx.x;
    const int base = blockIdx.x * SCAN_CHUNK + t * 16;
    int v[16];
    int s = 0;
    for (int k = 0; k < 16; ++k) {
        const int idx = base + k;
        v[k] = (idx < n) ? cnt[idx] : 0;
        s += v[k];
    }
    tsum[t] = s;
    __syncthreads();
    for (int d = 1; d < 256; d <<= 1) {
        const int y = (t >= d) ? tsum[t - d] : 0;
        __syncthreads();
        tsum[t] += y;
        __syncthreads();
    }
    int off = partials[blockIdx.x] + tsum[t] - s;   // exclusive prefix
    for (int k = 0; k < 16; ++k) {
        const int idx = base + k;
        if (idx < n) { ptr[idx] = off; cnt[idx] = off; }
        off += v[k];
    }
}

__global__ __launch_bounds__(256) void scatter_kernel(
    const int* __restrict__ rows, const int* __restrict__ cols,
    const float* __restrict__ vals,
    int* __restrict__ off_u, int* __restrict__ off_i,
    int2* __restrict__ pairs_u, int2* __restrict__ pairs_i, int nnz)
{
    int e = blockIdx.x * blockDim.x + threadIdx.x;
    if (e >= nnz) return;
    const int r = rows[e];
    const int c = cols[e];
    const int vb = __float_as_int(vals[e]);
    const int pu = atomicAdd(&off_u[r], 1);
    pairs_u[pu] = make_int2(c, vb);
    const int pi = atomicAdd(&off_i[c], 1);
    pairs_i[pi] = make_int2(r, vb);
}

// ---------------- SpMM: one 64-lane wave per destination row ----------------
// Lane l owns dims [2l,2l+1]. Edge pairs loaded coalesced (one per lane per
// 64-edge chunk), broadcast via __shfl. Dual dispatch: blocks [0,GU) do the
// user side, [GU,GU+GI) the item side. Epilogue: dst=acc;
// sum = (base ? base+acc : sum+acc) * scale.
__device__ __forceinline__ void spmm_row(
    const int* __restrict__ ptr, const int2* __restrict__ pairs,
    const float* __restrict__ src, float* __restrict__ dst,
    float* __restrict__ sum, const float* __restrict__ base,
    int row, int lane, float scale)
{
    const int start = ptr[row];
    const int end   = ptr[row + 1];
    float2 acc = make_float2(0.f, 0.f);

    for (int chunk = start; chunk < end; chunk += 64) {
        const int idx = chunk + lane;
        int2 p = make_int2(0, 0);
        if (idx < end) p = pairs[idx];
        int m = end - chunk; if (m > 64) m = 64;

        int j = 0;
        for (; j + 4 <= m; j += 4) {
            const int   c0 = __shfl(p.x, j),     c1 = __shfl(p.x, j + 1);
            const int   c2 = __shfl(p.x, j + 2), c3 = __shfl(p.x, j + 3);
            const float v0 = __int_as_float(__shfl(p.y, j));
            const float v1 = __int_as_float(__shfl(p.y, j + 1));
            const float v2 = __int_as_float(__shfl(p.y, j + 2));
            const float v3 = __int_as_float(__shfl(p.y, j + 3));
            const float2 s0 = *reinterpret_cast<const float2*>(src + (size_t)c0 * EMBED_DIM + (lane << 1));
            const float2 s1 = *reinterpret_cast<const float2*>(src + (size_t)c1 * EMBED_DIM + (lane << 1));
            const float2 s2 = *reinterpret_cast<const float2*>(src + (size_t)c2 * EMBED_DIM + (lane << 1));
            const float2 s3 = *reinterpret_cast<const float2*>(src + (size_t)c3 * EMBED_DIM + (lane << 1));
            acc.x += v0 * s0.x; acc.y += v0 * s0.y;
            acc.x += v1 * s1.x; acc.y += v1 * s1.y;
            acc.x += v2 * s2.x; acc.y += v2 * s2.y;
            acc.x += v3 * s3.x; acc.y += v3 * s3.y;
        }
        for (; j < m; ++j) {
            const int   c = __shfl(p.x, j);
            const float v = __int_as_float(__shfl(p.y, j));
            const float2 s = *reinterpret_cast<const float2*>(src + (size_t)c * EMBED_DIM + (lane << 1));
            acc.x += v * s.x; acc.y += v * s.y;
        }
    }

    const size_t o = (size_t)row * EMBED_DIM + (lane << 1);
    *reinterpret_cast<float2*>(dst + o) = acc;
    float2 b;
    if (base) b = *reinterpret_cast<const float2*>(base + o);
    else      b = *reinterpret_cast<const float2*>(sum + o);
    b.x = (b.x + acc.x) * scale;
    b.y = (b.y + acc.y) * scale;
    *reinterpret_cast<float2*>(sum + o) = b;
}

__global__ __launch_bounds__(256) void csr_spmm_dual(
    const int*  __restrict__ ptr_u, const int2* __restrict__ pairs_u,
    const float* __restrict__ src_u, float* __restrict__ dst_u,
    float* __restrict__ sum_u, const float* __restrict__ base_u,
    const int*  __restrict__ ptr_i, const int2* __restrict__ pairs_i,
    const float* __restrict__ src_i, float* __restrict__ dst_i,
    float* __restrict__ sum_i, const float* __restrict__ base_i,
    int GU, float scale)
{
    const int lane = threadIdx.x & 63;
    const int w = threadIdx.x >> 6;
    if ((int)blockIdx.x < GU) {
        const int row = blockIdx.x * 4 + w;
        if (row < NUM_USERS)
            spmm_row(ptr_u, pairs_u, src_u, dst_u, sum_u, base_u, row, lane, scale);
    } else {
        const int row = (blockIdx.x - GU) * 4 + w;
        if (row < NUM_ITEMS)
            spmm_row(ptr_i, pairs_i, src_i, dst_i, sum_i, base_i, row, lane, scale);
    }
}

// ---------------- fallback (round-1 atomic path) ----------------

__global__ __launch_bounds__(256) void edge_spmm(
    const float* __restrict__ vals, const int* __restrict__ rows,
    const int* __restrict__ cols, const float* __restrict__ u_src,
    const float* __restrict__ i_src, float* __restrict__ u_dst,
    float* __restrict__ i_dst, int nnz)
{
    const int lane = threadIdx.x & 31;
    const int e = blockIdx.x * 8 + (threadIdx.x >> 5);
    if (e >= nnz) return;
    const float v = vals[e];
    const size_t ro = (size_t)rows[e] * EMBED_DIM + lane * 4;
    const size_t co = (size_t)cols[e] * EMBED_DIM + lane * 4;
    const float4 iv = *reinterpret_cast<const float4*>(i_src + co);
    const float4 uv = *reinterpret_cast<const float4*>(u_src + ro);
    atomicAdd(u_dst + ro + 0, v * iv.x); atomicAdd(u_dst + ro + 1, v * iv.y);
    atomicAdd(u_dst + ro + 2, v * iv.z); atomicAdd(u_dst + ro + 3, v * iv.w);
    atomicAdd(i_dst + co + 0, v * uv.x); atomicAdd(i_dst + co + 1, v * uv.y);
    atomicAdd(i_dst + co + 2, v * uv.z); atomicAdd(i_dst + co + 3, v * uv.w);
}

__global__ __launch_bounds__(256) void acc_scale(
    float* __restrict__ out, const float* __restrict__ x, long n, float scale)
{
    long i = ((long)blockIdx.x * blockDim.x + threadIdx.x) * 4;
    if (i >= n) return;
    float4 o = *reinterpret_cast<float4*>(out + i);
    float4 a = *reinterpret_cast<const float4*>(x + i);
    o.x = (o.x + a.x) * scale; o.y = (o.y + a.y) * scale;
    o.z = (o.z + a.z) * scale; o.w = (o.w + a.w) * scale;
    *reinterpret_cast<float4*>(out + i) = o;
}

// ---------------- launch ----------------

extern "C" void kernel_launch(void* const* d_in, const int* in_sizes, int n_in,
                              void* d_out, int out_size, void* d_ws, size_t ws_size,
                              hipStream_t stream)
{
    const float* user = (const float*)d_in[0];
    const float* item = (const float*)d_in[1];
    const float* vals = (const float*)d_in[2];
    const int*   rows = (const int*)d_in[3];
    const int*   cols = (const int*)d_in[4];

    const size_t UD = (size_t)NUM_USERS * EMBED_DIM;
    const size_t ID = (size_t)NUM_ITEMS * EMBED_DIM;

    float* out_u = (float*)d_out;
    float* out_i = out_u + UD;

    // workspace layout
    char* ws = (char*)d_ws;
    float* uA = (float*)ws;                         ws += UD * 4;
    float* uB = (float*)ws;                         ws += UD * 4;
    float* iA = (float*)ws;                         ws += ID * 4;
    float* iB = (float*)ws;                         ws += ID * 4;
    int2* pairs_u = (int2*)ws;                      ws += (size_t)NNZ_COUNT * 8;
    int2* pairs_i = (int2*)ws;                      ws += (size_t)NNZ_COUNT * 8;
    int* ptr_u = (int*)ws;                          ws += (NUM_USERS + 1) * 4;
    int* cnt_u = (int*)ws;                          ws += NUM_USERS * 4;
    int* ptr_i = (int*)ws;                          ws += (NUM_ITEMS + 1) * 4;
    int* cnt_i = (int*)ws;                          ws += NUM_ITEMS * 4;
    int* part_u = (int*)ws;                         ws += 64 * 4;
    int* part_i = (int*)ws;                         ws += 64 * 4;
    const size_t REQ = (size_t)(ws - (char*)d_ws);

    const int EB = (NNZ_COUNT + 255) / 256;

    if (ws_size >= REQ) {
        // ---- CSR build (rows/cols layer-invariant: build once, use 6x) ----
        hipMemsetAsync(cnt_u, 0, NUM_USERS * 4, stream);
        hipMemsetAsync(cnt_i, 0, NUM_ITEMS * 4, stream);
        histo_kernel<<<EB, 256, 0, stream>>>(rows, cols, cnt_u, cnt_i, NNZ_COUNT);

        const int NBU = (NUM_USERS + SCAN_CHUNK - 1) / SCAN_CHUNK;   // 25
        const int NBI = (NUM_ITEMS + SCAN_CHUNK - 1) / SCAN_CHUNK;   // 13
        scan_partial_sums<<<NBU, 256, 0, stream>>>(cnt_u, part_u, NUM_USERS);
        scan_partial_sums<<<NBI, 256, 0, stream>>>(cnt_i, part_i, NUM_ITEMS);
        scan_partials_kernel<<<1, 64, 0, stream>>>(part_u, ptr_u + NUM_USERS, NBU);
        scan_partials_kernel<<<1, 64, 0, stream>>>(part_i, ptr_i + NUM_ITEMS, NBI);
        scan_chunk_kernel<<<NBU, 256, 0, stream>>>(cnt_u, part_u, ptr_u, NUM_USERS);
        scan_chunk_kernel<<<NBI, 256, 0, stream>>>(cnt_i, part_i, ptr_i, NUM_ITEMS);

        scatter_kernel<<<EB, 256, 0, stream>>>(rows, cols, vals, cnt_u, cnt_i,
                                               pairs_u, pairs_i, NNZ_COUNT);

        const int GU = (NUM_USERS + 3) / 4;   // 25000
        const int GI = (NUM_ITEMS + 3) / 4;   // 12500

        // layer 1: src = inputs; out_sum initialized from base (fused copy)
        csr_spmm_dual<<<GU + GI, 256, 0, stream>>>(
            ptr_u, pairs_u, item, uA, out_u, user,
            ptr_i, pairs_i, user, iA, out_i, item, GU, 1.0f);
        // layer 2
        csr_spmm_dual<<<GU + GI, 256, 0, stream>>>(
            ptr_u, pairs_u, iA, uB, out_u, nullptr,
            ptr_i, pairs_i, uA, iB, out_i, nullptr, GU, 1.0f);
        // layer 3 (+ final /4 fused)
        csr_spmm_dual<<<GU + GI, 256, 0, stream>>>(
            ptr_u, pairs_u, iB, uA, out_u, nullptr,
            ptr_i, pairs_i, uB, iA, out_i, nullptr, GU, 0.25f);
    } else {
        // ---- fallback: round-1 atomic path ----
        const int EDGE_BLOCKS = (NNZ_COUNT + 7) / 8;
        const int ACC_U = (int)(UD / 1024), ACC_I = (int)(ID / 1024);

        hipMemcpyAsync(out_u, user, UD * 4, hipMemcpyDeviceToDevice, stream);
        hipMemcpyAsync(out_i, item, ID * 4, hipMemcpyDeviceToDevice, stream);

        hipMemsetAsync(uA, 0, UD * 4, stream);
        hipMemsetAsync(iA, 0, ID * 4, stream);
        edge_spmm<<<EDGE_BLOCKS, 256, 0, stream>>>(vals, rows, cols, user, item, uA, iA, NNZ_COUNT);
        acc_scale<<<ACC_U, 256, 0, stream>>>(out_u, uA, (long)UD, 1.0f);
        acc_scale<<<ACC_I, 256, 0, stream>>>(out_i, iA, (long)ID, 1.0f);

        hipMemsetAsync(uB, 0, UD * 4, stream);
        hipMemsetAsync(iB, 0, ID * 4, stream);
        edge_spmm<<<EDGE_BLOCKS, 256, 0, stream>>>(vals, rows, cols, uA, iA, uB, iB, NNZ_COUNT);
        acc_scale<<<ACC_U, 256, 0, stream>>>(out_u, uB, (long)UD, 1.0f);
        acc_scale<<<ACC_I, 256, 0, stream>>>(out_i, iB, (long)ID, 1.0f);

        hipMemsetAsync(uA, 0, UD * 4, stream);
        hipMemsetAsync(iA, 0, ID * 4, stream);
        edge_spmm<<<EDGE_BLOCKS, 256, 0, stream>>>(vals, rows, cols, uB, iB, uA, iA, NNZ_COUNT);
        acc_scale<<<ACC_U, 256, 0, stream>>>(out_u, uA, (long)UD, 0.25f);
        acc_scale<<<ACC_I, 256, 0, stream>>>(out_i, iA, (long)ID, 0.25f);
    }
}